// Round 1
// baseline (920.121 us; speedup 1.0000x reference)
//
#include <hip/hip_runtime.h>
#include <math.h>

#define NCLS 16
#define DIM  64

// ---------------- K1a: init counters + Gram buffer ----------------
__global__ void k_init(int* __restrict__ cnt, float* __restrict__ G) {
    int t = blockIdx.x * blockDim.x + threadIdx.x;
    if (t < NCLS) cnt[t] = 0;
    for (int i = t; i < NCLS * DIM * DIM; i += gridDim.x * blockDim.x) G[i] = 0.f;
}

// ---------------- K1b: class histogram (block-aggregated) ----------------
__global__ void k_hist(const int* __restrict__ label, int n, int* __restrict__ cnt) {
    __shared__ int h[NCLS];
    if (threadIdx.x < NCLS) h[threadIdx.x] = 0;
    __syncthreads();
    int stride = gridDim.x * blockDim.x;
    for (int i = blockIdx.x * blockDim.x + threadIdx.x; i < n; i += stride)
        atomicAdd(&h[label[i]], 1);
    __syncthreads();
    if (threadIdx.x < NCLS) atomicAdd(&cnt[threadIdx.x], h[threadIdx.x]);
}

// ---------------- K1c: tiny exclusive scan ----------------
__global__ void k_scan(const int* __restrict__ cnt, int* __restrict__ base,
                       int* __restrict__ cursor) {
    if (threadIdx.x == 0) {
        int s = 0;
        for (int c = 0; c < NCLS; c++) { base[c] = s; cursor[c] = s; s += cnt[c]; }
    }
}

// ---------------- K1d: scatter row indices into class buckets ----------------
__global__ void k_scatter(const int* __restrict__ label, int n,
                          int* __restrict__ cursor, int* __restrict__ idx) {
    __shared__ int h[NCLS];
    __shared__ int cur[NCLS];
    if (threadIdx.x < NCLS) h[threadIdx.x] = 0;
    __syncthreads();
    int stride = gridDim.x * blockDim.x;
    for (int i = blockIdx.x * blockDim.x + threadIdx.x; i < n; i += stride)
        atomicAdd(&h[label[i]], 1);
    __syncthreads();
    if (threadIdx.x < NCLS)
        cur[threadIdx.x] = atomicAdd(&cursor[threadIdx.x], h[threadIdx.x]);
    __syncthreads();
    for (int i = blockIdx.x * blockDim.x + threadIdx.x; i < n; i += stride) {
        int p = atomicAdd(&cur[label[i]], 1);
        idx[p] = i;
    }
}

// ---------------- K2: per-class Gram via register 8x8 tiles ----------------
// grid = 16 classes * 32 blocks, block = 256 (4 waves). Each wave owns the full
// 64x64 outer product (8x8 per lane), processes 8 rows per iteration for ILP.
__global__ __launch_bounds__(256) void k_gram(const float* __restrict__ feat,
                                              const int* __restrict__ idx,
                                              const int* __restrict__ base,
                                              const int* __restrict__ cnt,
                                              float* __restrict__ G) {
    const int c    = blockIdx.x & (NCLS - 1);
    const int blk  = blockIdx.x >> 4;          // 0..31
    const int wave = threadIdx.x >> 6;         // 0..3
    const int lane = threadIdx.x & 63;
    const int gw   = blk * 4 + wave;           // 0..127
    const int r0   = (lane >> 3) << 3;
    const int c0   = (lane & 7) << 3;
    const int m    = cnt[c];
    const int b0   = base[c];
    const int STEP = 128 * 8;

    float acc[8][8];
#pragma unroll
    for (int j = 0; j < 8; j++)
#pragma unroll
        for (int k = 0; k < 8; k++) acc[j][k] = 0.f;

    int ii[8];
    const int p0 = gw * 8;
#pragma unroll
    for (int q = 0; q < 8; q++) ii[q] = (p0 + q < m) ? idx[b0 + p0 + q] : -1;

    for (int p = p0; p < m; p += STEP) {
        float4 xa[8][2], xb[8][2];
#pragma unroll
        for (int q = 0; q < 8; q++) {
            if (ii[q] >= 0) {
                const float* rp = feat + (size_t)ii[q] * DIM;
                xa[q][0] = *(const float4*)(rp + r0);
                xa[q][1] = *(const float4*)(rp + r0 + 4);
                xb[q][0] = *(const float4*)(rp + c0);
                xb[q][1] = *(const float4*)(rp + c0 + 4);
            } else {
                float4 z = make_float4(0.f, 0.f, 0.f, 0.f);
                xa[q][0] = z; xa[q][1] = z; xb[q][0] = z; xb[q][1] = z;
            }
        }
        // prefetch next group's indices (covered by the fmac burst below)
        const int pn = p + STEP;
#pragma unroll
        for (int q = 0; q < 8; q++) ii[q] = (pn + q < m) ? idx[b0 + pn + q] : -1;

#pragma unroll
        for (int q = 0; q < 8; q++) {
            float av[8] = {xa[q][0].x, xa[q][0].y, xa[q][0].z, xa[q][0].w,
                           xa[q][1].x, xa[q][1].y, xa[q][1].z, xa[q][1].w};
            float bv[8] = {xb[q][0].x, xb[q][0].y, xb[q][0].z, xb[q][0].w,
                           xb[q][1].x, xb[q][1].y, xb[q][1].z, xb[q][1].w};
#pragma unroll
            for (int j = 0; j < 8; j++)
#pragma unroll
                for (int k = 0; k < 8; k++)
                    acc[j][k] = fmaf(av[j], bv[k], acc[j][k]);
        }
    }

    float* g = G + c * DIM * DIM;
#pragma unroll
    for (int j = 0; j < 8; j++)
#pragma unroll
        for (int k = 0; k < 8; k++)
            atomicAdd(&g[(r0 + j) * DIM + (c0 + k)], acc[j][k]);
}

// ---------------- K3: top eigenvector per class ----------------
// One 64-lane wave per class. G row r lives in lane r's VGPRs; the iterate is
// kept replicated in every lane (matvec = 64 in-reg fmacs), all-gather via LDS.
// Shifted power iteration; shifted matrix is squared 3x (A -> A^8) so each of
// the 152 final applies contracts at ratio^8 (robust to small top-edge gaps).
__global__ __launch_bounds__(64) void k_eig(const float* __restrict__ G,
                                            float* __restrict__ V) {
    const int c    = blockIdx.x;
    const int lane = threadIdx.x;
    __shared__ float shA[DIM * DIM];       // stride-64, b128-aligned rows
    __shared__ float shB[DIM * 65];        // stride-65 copy: conflict-free f-read

    float row[DIM];
    {
        const float4* g4 = (const float4*)(G + c * DIM * DIM + lane * DIM);
#pragma unroll
        for (int j = 0; j < 16; j++) {
            float4 t = g4[j];
            row[4 * j + 0] = t.x; row[4 * j + 1] = t.y;
            row[4 * j + 2] = t.z; row[4 * j + 3] = t.w;
        }
    }

    float v[DIM];
    float vd;
    auto init_v = [&]() {
#pragma unroll
        for (int j = 0; j < DIM; j++) v[j] = 1.0f + 0.11f * (float)((j * 13) & 7);
        vd = 1.0f + 0.11f * (float)((lane * 13) & 7);
    };

    // y = (M - shift I) v with M = rows in `row`; gather; optional normalize.
    auto apply = [&](float shift, bool norm) -> float {
        float y0 = 0, y1 = 0, y2 = 0, y3 = 0;
#pragma unroll
        for (int j = 0; j < DIM; j += 4) {
            y0 = fmaf(row[j + 0], v[j + 0], y0);
            y1 = fmaf(row[j + 1], v[j + 1], y1);
            y2 = fmaf(row[j + 2], v[j + 2], y2);
            y3 = fmaf(row[j + 3], v[j + 3], y3);
        }
        float y = ((y0 + y1) + (y2 + y3)) - shift * vd;
        __syncthreads();
        shA[lane] = y;
        __syncthreads();
        const float4* s4 = (const float4*)shA;
#pragma unroll
        for (int j = 0; j < 16; j++) {
            float4 t = s4[j];
            v[4 * j + 0] = t.x; v[4 * j + 1] = t.y;
            v[4 * j + 2] = t.z; v[4 * j + 3] = t.w;
        }
        vd = y;
        float r = 0.f;
        if (norm) {
            float n0 = 0, n1 = 0, n2 = 0, n3 = 0;
#pragma unroll
            for (int j = 0; j < DIM; j += 4) {
                n0 = fmaf(v[j + 0], v[j + 0], n0);
                n1 = fmaf(v[j + 1], v[j + 1], n1);
                n2 = fmaf(v[j + 2], v[j + 2], n2);
                n3 = fmaf(v[j + 3], v[j + 3], n3);
            }
            float nn = (n0 + n1) + (n2 + n3);
            float inv = (nn > 1e-30f) ? rsqrtf(nn) : 1.0f;
#pragma unroll
            for (int j = 0; j < DIM; j++) v[j] *= inv;
            vd *= inv;
            r = sqrtf(nn);
        }
        return r;
    };

    // --- estimate lambda1 (||Gv|| after a few normalized power steps) ---
    init_v();
    float lam1 = 1.0f;
    for (int it = 0; it < 13; it++) lam1 = apply(0.f, true);
    // --- estimate lambda_min via dominant |.| of (G - lam1 I) ---
    float mu = 0.f;
    for (int it = 0; it < 13; it++) mu = apply(lam1, true);
    float lamin = lam1 - mu;
    float sigma = lamin + 0.45f * (lam1 - lamin);

    // --- square the shifted matrix 3 times: row <- ((G-sigma I))^8, rescaled ---
    float curshift = sigma;
    for (int sq = 0; sq < 3; sq++) {
        __syncthreads();
        {
            float4* a4 = (float4*)(shA) + lane * 16;
#pragma unroll
            for (int j4 = 0; j4 < 16; j4++) {
                float4 t;
                t.x = row[4 * j4 + 0] - ((4 * j4 + 0) == lane ? curshift : 0.f);
                t.y = row[4 * j4 + 1] - ((4 * j4 + 1) == lane ? curshift : 0.f);
                t.z = row[4 * j4 + 2] - ((4 * j4 + 2) == lane ? curshift : 0.f);
                t.w = row[4 * j4 + 3] - ((4 * j4 + 3) == lane ? curshift : 0.f);
                a4[j4] = t;
                shB[lane * 65 + 4 * j4 + 0] = t.x;
                shB[lane * 65 + 4 * j4 + 1] = t.y;
                shB[lane * 65 + 4 * j4 + 2] = t.z;
                shB[lane * 65 + 4 * j4 + 3] = t.w;
            }
        }
        __syncthreads();
        float h[DIM];
#pragma unroll
        for (int j = 0; j < DIM; j++) h[j] = 0.f;
        for (int k = 0; k < DIM; k++) {
            float f = shB[lane * 65 + k];              // A[lane][k], conflict-free
            const float4* ak = (const float4*)(shA + k * DIM);  // broadcast row k
#pragma unroll
            for (int j4 = 0; j4 < 16; j4++) {
                float4 t = ak[j4];
                h[4 * j4 + 0] = fmaf(f, t.x, h[4 * j4 + 0]);
                h[4 * j4 + 1] = fmaf(f, t.y, h[4 * j4 + 1]);
                h[4 * j4 + 2] = fmaf(f, t.z, h[4 * j4 + 2]);
                h[4 * j4 + 3] = fmaf(f, t.w, h[4 * j4 + 3]);
            }
        }
        // rescale by 1/max|h| (uniform across lanes) to avoid overflow
        float mx = 0.f;
#pragma unroll
        for (int j = 0; j < DIM; j++) mx = fmaxf(mx, fabsf(h[j]));
        __syncthreads();
        shA[lane] = mx;
        __syncthreads();
        float gm = 0.f;
        {
            const float4* s4 = (const float4*)shA;
#pragma unroll
            for (int j4 = 0; j4 < 16; j4++) {
                float4 t = s4[j4];
                gm = fmaxf(gm, fmaxf(fmaxf(t.x, t.y), fmaxf(t.z, t.w)));
            }
        }
        float inv = (gm > 0.f) ? (1.0f / gm) : 1.0f;
#pragma unroll
        for (int j = 0; j < DIM; j++) row[j] = h[j] * inv;
        curshift = 0.f;
    }

    // --- final power iteration on the squared/shifted matrix ---
    init_v();
    for (int it = 0; it < 152; it++) apply(0.f, (it & 3) == 3);

    // --- sign convention: component with largest |.| made positive ---
    float bm = -1.f, bv = 0.f;
#pragma unroll
    for (int j = 0; j < DIM; j++) {
        float a = fabsf(v[j]);
        if (a > bm) { bm = a; bv = v[j]; }
    }
    float s = (bv < 0.f) ? -1.f : 1.f;
    V[c * DIM + lane] = vd * s;
}

// ---------------- K4: given[i] = <feat_i, V[label_i]> ----------------
__global__ __launch_bounds__(256) void k_out(const float* __restrict__ feat,
                                             const int* __restrict__ label,
                                             const float* __restrict__ V,
                                             float* __restrict__ out, int n) {
    int i = blockIdx.x * blockDim.x + threadIdx.x;
    if (i >= n) return;
    const float4* rp = (const float4*)(feat + (size_t)i * DIM);
    const float4* vp = (const float4*)(V + label[i] * DIM);
    float s0 = 0, s1 = 0, s2 = 0, s3 = 0;
#pragma unroll
    for (int j = 0; j < 16; j++) {
        float4 a = rp[j], b = vp[j];
        s0 = fmaf(a.x, b.x, s0);
        s1 = fmaf(a.y, b.y, s1);
        s2 = fmaf(a.z, b.z, s2);
        s3 = fmaf(a.w, b.w, s3);
    }
    out[i] = (s0 + s1) + (s2 + s3);
}

extern "C" void kernel_launch(void* const* d_in, const int* in_sizes, int n_in,
                              void* d_out, int out_size, void* d_ws, size_t ws_size,
                              hipStream_t stream) {
    const float* feat  = (const float*)d_in[0];
    const int*   label = (const int*)d_in[1];
    const int    n     = in_sizes[1];
    float*       out   = (float*)d_out;

    // workspace layout (~2.3 MB)
    int*   cnt    = (int*)d_ws;
    int*   base   = cnt + 16;
    int*   cursor = cnt + 32;
    float* G      = (float*)(cnt + 64);          // 16 * 4096 floats
    float* V      = G + NCLS * DIM * DIM;        // 16 * 64 floats
    int*   idx    = (int*)(V + NCLS * DIM);      // n ints

    k_init<<<64, 256, 0, stream>>>(cnt, G);
    k_hist<<<256, 256, 0, stream>>>(label, n, cnt);
    k_scan<<<1, 64, 0, stream>>>(cnt, base, cursor);
    k_scatter<<<256, 256, 0, stream>>>(label, n, cursor, idx);
    k_gram<<<NCLS * 32, 256, 0, stream>>>(feat, idx, base, cnt, G);
    k_eig<<<NCLS, 64, 0, stream>>>(G, V);
    k_out<<<(n + 255) / 256, 256, 0, stream>>>(feat, label, V, out, n);
}

// Round 2
// 501.884 us; speedup vs baseline: 1.8333x; 1.8333x over previous
//
#include <hip/hip_runtime.h>
#include <math.h>

#define NCLS 16
#define DIM  64

// ---------------- K1a: init counters + Gram buffer ----------------
__global__ void k_init(int* __restrict__ cnt, float* __restrict__ G) {
    int t = blockIdx.x * blockDim.x + threadIdx.x;
    if (t < NCLS) cnt[t] = 0;
    for (int i = t; i < NCLS * DIM * DIM; i += gridDim.x * blockDim.x) G[i] = 0.f;
}

// ---------------- K1b: class histogram (block-aggregated) ----------------
__global__ void k_hist(const int* __restrict__ label, int n, int* __restrict__ cnt) {
    __shared__ int h[NCLS];
    if (threadIdx.x < NCLS) h[threadIdx.x] = 0;
    __syncthreads();
    int stride = gridDim.x * blockDim.x;
    for (int i = blockIdx.x * blockDim.x + threadIdx.x; i < n; i += stride)
        atomicAdd(&h[label[i]], 1);
    __syncthreads();
    if (threadIdx.x < NCLS) atomicAdd(&cnt[threadIdx.x], h[threadIdx.x]);
}

// ---------------- K1c: tiny exclusive scan ----------------
__global__ void k_scan(const int* __restrict__ cnt, int* __restrict__ base,
                       int* __restrict__ cursor) {
    if (threadIdx.x == 0) {
        int s = 0;
        for (int c = 0; c < NCLS; c++) { base[c] = s; cursor[c] = s; s += cnt[c]; }
    }
}

// ---------------- K1d: scatter row indices into class buckets ----------------
__global__ void k_scatter(const int* __restrict__ label, int n,
                          int* __restrict__ cursor, int* __restrict__ idx) {
    __shared__ int h[NCLS];
    __shared__ int cur[NCLS];
    if (threadIdx.x < NCLS) h[threadIdx.x] = 0;
    __syncthreads();
    int stride = gridDim.x * blockDim.x;
    for (int i = blockIdx.x * blockDim.x + threadIdx.x; i < n; i += stride)
        atomicAdd(&h[label[i]], 1);
    __syncthreads();
    if (threadIdx.x < NCLS)
        cur[threadIdx.x] = atomicAdd(&cursor[threadIdx.x], h[threadIdx.x]);
    __syncthreads();
    for (int i = blockIdx.x * blockDim.x + threadIdx.x; i < n; i += stride) {
        int p = atomicAdd(&cur[label[i]], 1);
        idx[p] = i;
    }
}

// ---------------- K2: per-class Gram via register 8x8 tiles ----------------
// grid = 16 classes * 64 blocks, block = 256 (4 waves). Each wave owns the full
// 64x64 outer product (8x8 per lane), 2 rows per iteration (q=2 keeps the load
// buffers at 32 VGPRs: 64 acc + 32 loads + misc ~ 112 fits the 128-VGPR cap
// from __launch_bounds__(256,4); q=8 spilled 268 MB of scratch traffic).
// Epilogue: phased (race-free, no atomics) LDS block reduction, then 4096
// coalesced global atomics per block instead of 16K.
__global__ __launch_bounds__(256, 4) void k_gram(const float* __restrict__ feat,
                                                 const int* __restrict__ idx,
                                                 const int* __restrict__ base,
                                                 const int* __restrict__ cnt,
                                                 float* __restrict__ G) {
    const int c    = blockIdx.x & (NCLS - 1);
    const int blk  = blockIdx.x >> 4;          // 0..63
    const int wave = threadIdx.x >> 6;         // 0..3
    const int lane = threadIdx.x & 63;
    const int gw   = blk * 4 + wave;           // 0..255
    const int r0   = (lane >> 3) << 3;
    const int c0   = (lane & 7) << 3;
    const int m    = cnt[c];
    const int b0   = base[c];
    const int STEP = 256 * 2;                  // waves-per-class * q

    float acc[8][8];
#pragma unroll
    for (int j = 0; j < 8; j++)
#pragma unroll
        for (int k = 0; k < 8; k++) acc[j][k] = 0.f;

    int ii[2];
    const int p0 = gw * 2;
#pragma unroll
    for (int q = 0; q < 2; q++) ii[q] = (p0 + q < m) ? idx[b0 + p0 + q] : -1;

    for (int p = p0; p < m; p += STEP) {
        float4 xa[2][2], xb[2][2];
#pragma unroll
        for (int q = 0; q < 2; q++) {
            if (ii[q] >= 0) {                  // wave-uniform branch
                const float* rp = feat + (size_t)ii[q] * DIM;
                xa[q][0] = *(const float4*)(rp + r0);
                xa[q][1] = *(const float4*)(rp + r0 + 4);
                xb[q][0] = *(const float4*)(rp + c0);
                xb[q][1] = *(const float4*)(rp + c0 + 4);
            } else {
                float4 z = make_float4(0.f, 0.f, 0.f, 0.f);
                xa[q][0] = z; xa[q][1] = z; xb[q][0] = z; xb[q][1] = z;
            }
        }
        // prefetch next group's indices (covered by the fmac burst below)
        const int pn = p + STEP;
#pragma unroll
        for (int q = 0; q < 2; q++) ii[q] = (pn + q < m) ? idx[b0 + pn + q] : -1;

#pragma unroll
        for (int q = 0; q < 2; q++) {
            float av[8] = {xa[q][0].x, xa[q][0].y, xa[q][0].z, xa[q][0].w,
                           xa[q][1].x, xa[q][1].y, xa[q][1].z, xa[q][1].w};
            float bv[8] = {xb[q][0].x, xb[q][0].y, xb[q][0].z, xb[q][0].w,
                           xb[q][1].x, xb[q][1].y, xb[q][1].z, xb[q][1].w};
#pragma unroll
            for (int j = 0; j < 8; j++)
#pragma unroll
                for (int k = 0; k < 8; k++)
                    acc[j][k] = fmaf(av[j], bv[k], acc[j][k]);
        }
    }

    // ---- phased LDS block reduction (each lane owns the same 8x8 elements
    //      in every wave -> no races, no LDS atomics) ----
    __shared__ float tile[DIM * DIM];
    for (int w = 0; w < 4; w++) {
        if (wave == w) {
            float* t = tile + r0 * DIM + c0;
            if (w == 0) {
#pragma unroll
                for (int j = 0; j < 8; j++) {
                    *(float4*)(t + j * DIM)     = make_float4(acc[j][0], acc[j][1], acc[j][2], acc[j][3]);
                    *(float4*)(t + j * DIM + 4) = make_float4(acc[j][4], acc[j][5], acc[j][6], acc[j][7]);
                }
            } else {
#pragma unroll
                for (int j = 0; j < 8; j++) {
                    float4 u0 = *(float4*)(t + j * DIM);
                    float4 u1 = *(float4*)(t + j * DIM + 4);
                    u0.x += acc[j][0]; u0.y += acc[j][1]; u0.z += acc[j][2]; u0.w += acc[j][3];
                    u1.x += acc[j][4]; u1.y += acc[j][5]; u1.z += acc[j][6]; u1.w += acc[j][7];
                    *(float4*)(t + j * DIM)     = u0;
                    *(float4*)(t + j * DIM + 4) = u1;
                }
            }
        }
        __syncthreads();
    }
    float* g = G + c * DIM * DIM;
    for (int e = threadIdx.x; e < DIM * DIM; e += 256)
        atomicAdd(&g[e], tile[e]);
}

// ---------------- K3: top eigenvector per class ----------------
// One 64-lane wave per class. G row r lives in lane r's VGPRs; the iterate is
// kept replicated in every lane (matvec = 64 in-reg fmacs), all-gather via LDS.
// Shifted power iteration; shifted matrix is squared 3x (A -> A^8) so each of
// the 152 final applies contracts at ratio^8 (robust to small top-edge gaps).
__global__ __launch_bounds__(64) void k_eig(const float* __restrict__ G,
                                            float* __restrict__ V) {
    const int c    = blockIdx.x;
    const int lane = threadIdx.x;
    __shared__ float shA[DIM * DIM];       // stride-64, b128-aligned rows
    __shared__ float shB[DIM * 65];        // stride-65 copy: conflict-free f-read

    float row[DIM];
    {
        const float4* g4 = (const float4*)(G + c * DIM * DIM + lane * DIM);
#pragma unroll
        for (int j = 0; j < 16; j++) {
            float4 t = g4[j];
            row[4 * j + 0] = t.x; row[4 * j + 1] = t.y;
            row[4 * j + 2] = t.z; row[4 * j + 3] = t.w;
        }
    }

    float v[DIM];
    float vd;
    auto init_v = [&]() {
#pragma unroll
        for (int j = 0; j < DIM; j++) v[j] = 1.0f + 0.11f * (float)((j * 13) & 7);
        vd = 1.0f + 0.11f * (float)((lane * 13) & 7);
    };

    // y = (M - shift I) v with M = rows in `row`; gather; optional normalize.
    auto apply = [&](float shift, bool norm) -> float {
        float y0 = 0, y1 = 0, y2 = 0, y3 = 0;
#pragma unroll
        for (int j = 0; j < DIM; j += 4) {
            y0 = fmaf(row[j + 0], v[j + 0], y0);
            y1 = fmaf(row[j + 1], v[j + 1], y1);
            y2 = fmaf(row[j + 2], v[j + 2], y2);
            y3 = fmaf(row[j + 3], v[j + 3], y3);
        }
        float y = ((y0 + y1) + (y2 + y3)) - shift * vd;
        __syncthreads();
        shA[lane] = y;
        __syncthreads();
        const float4* s4 = (const float4*)shA;
#pragma unroll
        for (int j = 0; j < 16; j++) {
            float4 t = s4[j];
            v[4 * j + 0] = t.x; v[4 * j + 1] = t.y;
            v[4 * j + 2] = t.z; v[4 * j + 3] = t.w;
        }
        vd = y;
        float r = 0.f;
        if (norm) {
            float n0 = 0, n1 = 0, n2 = 0, n3 = 0;
#pragma unroll
            for (int j = 0; j < DIM; j += 4) {
                n0 = fmaf(v[j + 0], v[j + 0], n0);
                n1 = fmaf(v[j + 1], v[j + 1], n1);
                n2 = fmaf(v[j + 2], v[j + 2], n2);
                n3 = fmaf(v[j + 3], v[j + 3], n3);
            }
            float nn = (n0 + n1) + (n2 + n3);
            float inv = (nn > 1e-30f) ? rsqrtf(nn) : 1.0f;
#pragma unroll
            for (int j = 0; j < DIM; j++) v[j] *= inv;
            vd *= inv;
            r = sqrtf(nn);
        }
        return r;
    };

    // --- estimate lambda1 (||Gv|| after a few normalized power steps) ---
    init_v();
    float lam1 = 1.0f;
    for (int it = 0; it < 13; it++) lam1 = apply(0.f, true);
    // --- estimate lambda_min via dominant |.| of (G - lam1 I) ---
    float mu = 0.f;
    for (int it = 0; it < 13; it++) mu = apply(lam1, true);
    float lamin = lam1 - mu;
    float sigma = lamin + 0.45f * (lam1 - lamin);

    // --- square the shifted matrix 3 times: row <- ((G-sigma I))^8, rescaled ---
    float curshift = sigma;
    for (int sq = 0; sq < 3; sq++) {
        __syncthreads();
        {
            float4* a4 = (float4*)(shA) + lane * 16;
#pragma unroll
            for (int j4 = 0; j4 < 16; j4++) {
                float4 t;
                t.x = row[4 * j4 + 0] - ((4 * j4 + 0) == lane ? curshift : 0.f);
                t.y = row[4 * j4 + 1] - ((4 * j4 + 1) == lane ? curshift : 0.f);
                t.z = row[4 * j4 + 2] - ((4 * j4 + 2) == lane ? curshift : 0.f);
                t.w = row[4 * j4 + 3] - ((4 * j4 + 3) == lane ? curshift : 0.f);
                a4[j4] = t;
                shB[lane * 65 + 4 * j4 + 0] = t.x;
                shB[lane * 65 + 4 * j4 + 1] = t.y;
                shB[lane * 65 + 4 * j4 + 2] = t.z;
                shB[lane * 65 + 4 * j4 + 3] = t.w;
            }
        }
        __syncthreads();
        float h[DIM];
#pragma unroll
        for (int j = 0; j < DIM; j++) h[j] = 0.f;
        for (int k = 0; k < DIM; k++) {
            float f = shB[lane * 65 + k];              // A[lane][k], conflict-free
            const float4* ak = (const float4*)(shA + k * DIM);  // broadcast row k
#pragma unroll
            for (int j4 = 0; j4 < 16; j4++) {
                float4 t = ak[j4];
                h[4 * j4 + 0] = fmaf(f, t.x, h[4 * j4 + 0]);
                h[4 * j4 + 1] = fmaf(f, t.y, h[4 * j4 + 1]);
                h[4 * j4 + 2] = fmaf(f, t.z, h[4 * j4 + 2]);
                h[4 * j4 + 3] = fmaf(f, t.w, h[4 * j4 + 3]);
            }
        }
        // rescale by 1/max|h| (uniform across lanes) to avoid overflow
        float mx = 0.f;
#pragma unroll
        for (int j = 0; j < DIM; j++) mx = fmaxf(mx, fabsf(h[j]));
        __syncthreads();
        shA[lane] = mx;
        __syncthreads();
        float gm = 0.f;
        {
            const float4* s4 = (const float4*)shA;
#pragma unroll
            for (int j4 = 0; j4 < 16; j4++) {
                float4 t = s4[j4];
                gm = fmaxf(gm, fmaxf(fmaxf(t.x, t.y), fmaxf(t.z, t.w)));
            }
        }
        float inv = (gm > 0.f) ? (1.0f / gm) : 1.0f;
#pragma unroll
        for (int j = 0; j < DIM; j++) row[j] = h[j] * inv;
        curshift = 0.f;
    }

    // --- final power iteration on the squared/shifted matrix ---
    init_v();
    for (int it = 0; it < 152; it++) apply(0.f, (it & 3) == 3);

    // --- sign convention: component with largest |.| made positive ---
    float bm = -1.f, bv = 0.f;
#pragma unroll
    for (int j = 0; j < DIM; j++) {
        float a = fabsf(v[j]);
        if (a > bm) { bm = a; bv = v[j]; }
    }
    float s = (bv < 0.f) ? -1.f : 1.f;
    V[c * DIM + lane] = vd * s;
}

// ---------------- K4: given[i] = <feat_i, V[label_i]> ----------------
__global__ __launch_bounds__(256) void k_out(const float* __restrict__ feat,
                                             const int* __restrict__ label,
                                             const float* __restrict__ V,
                                             float* __restrict__ out, int n) {
    int i = blockIdx.x * blockDim.x + threadIdx.x;
    if (i >= n) return;
    const float4* rp = (const float4*)(feat + (size_t)i * DIM);
    const float4* vp = (const float4*)(V + label[i] * DIM);
    float s0 = 0, s1 = 0, s2 = 0, s3 = 0;
#pragma unroll
    for (int j = 0; j < 16; j++) {
        float4 a = rp[j], b = vp[j];
        s0 = fmaf(a.x, b.x, s0);
        s1 = fmaf(a.y, b.y, s1);
        s2 = fmaf(a.z, b.z, s2);
        s3 = fmaf(a.w, b.w, s3);
    }
    out[i] = (s0 + s1) + (s2 + s3);
}

extern "C" void kernel_launch(void* const* d_in, const int* in_sizes, int n_in,
                              void* d_out, int out_size, void* d_ws, size_t ws_size,
                              hipStream_t stream) {
    const float* feat  = (const float*)d_in[0];
    const int*   label = (const int*)d_in[1];
    const int    n     = in_sizes[1];
    float*       out   = (float*)d_out;

    // workspace layout (~2.3 MB)
    int*   cnt    = (int*)d_ws;
    int*   base   = cnt + 16;
    int*   cursor = cnt + 32;
    float* G      = (float*)(cnt + 64);          // 16 * 4096 floats
    float* V      = G + NCLS * DIM * DIM;        // 16 * 64 floats
    int*   idx    = (int*)(V + NCLS * DIM);      // n ints

    k_init<<<64, 256, 0, stream>>>(cnt, G);
    k_hist<<<256, 256, 0, stream>>>(label, n, cnt);
    k_scan<<<1, 64, 0, stream>>>(cnt, base, cursor);
    k_scatter<<<256, 256, 0, stream>>>(label, n, cursor, idx);
    k_gram<<<NCLS * 64, 256, 0, stream>>>(feat, idx, base, cnt, G);
    k_eig<<<NCLS, 64, 0, stream>>>(G, V);
    k_out<<<(n + 255) / 256, 256, 0, stream>>>(feat, label, V, out, n);
}